// Round 7
// baseline (102.780 us; speedup 1.0000x reference)
//
#include <hip/hip_runtime.h>
#include <hip/hip_bf16.h>

typedef __attribute__((ext_vector_type(8))) __bf16 bf16x8;
typedef __attribute__((ext_vector_type(4))) __bf16 bf16x4;
typedef __attribute__((ext_vector_type(4))) float f32x4;

#define DIN 1024
#define DOUT 1024
#define BB 4
#define SS 4096
#define MROWS (BB*SS)   /* 16384 */
#define POOLN 5
#define RR 8
#define NTASKS 5
#define TOPKK 3

// ---------------- K1a: streaming colsum-partials + f32->bf16 convert ----------
__global__ __launch_bounds__(256) void k1a_stream(const float* __restrict__ in,
                                                  __bf16* __restrict__ inB,
                                                  float* __restrict__ partial) {
    const int t = threadIdx.x;
    const int b = blockIdx.x;
    const int idx0 = b * 256 + t;                        // 0..524287
    const float4* __restrict__ inv = (const float4*)in;
    bf16x4* __restrict__ outv = (bf16x4*)inB;

    float s0 = 0.f, s1 = 0.f, s2 = 0.f, s3 = 0.f;
    size_t idx = idx0;
    float4 cur = inv[idx];
#pragma unroll
    for (int it = 0; it < 8; ++it) {
        float4 nxt = cur;
        if (it < 7) nxt = inv[idx + 524288];             // prefetch next before use
        s0 += cur.x; s1 += cur.y; s2 += cur.z; s3 += cur.w;
        bf16x4 bb = { (__bf16)cur.x, (__bf16)cur.y, (__bf16)cur.z, (__bf16)cur.w };
        outv[idx] = bb;
        cur = nxt;
        idx += 524288;
    }
    float4 p = { s0, s1, s2, s3 };
    *(float4*)&partial[(size_t)b * DIN + t * 4] = p;     // coalesced float4 store
}

// ---------------- K1b: reduce partial[2048][1024] -> colsum[1024] -------------
__global__ __launch_bounds__(256) void k1b_reduce(const float* __restrict__ partial,
                                                  float* __restrict__ colsum) {
    const int tid = blockIdx.x * 256 + threadIdx.x;      // 0..8191
    const int c = tid & (DIN - 1);
    const int g = tid >> 10;                             // 0..7
    float s = 0.f;
    const int b0 = g * 256;
#pragma unroll 8
    for (int b = b0; b < b0 + 256; ++b)
        s += partial[(size_t)b * DIN + c];
    atomicAdd(&colsum[c], s);
}

// ---------------- K2: omegas -> top-k -> softmax gate ----------------
__global__ void k2_gate(const float* __restrict__ colsum,
                        const float* __restrict__ lroute,
                        const int* __restrict__ task_id_p,
                        float* __restrict__ gate, int* __restrict__ gidx) {
    const int l = threadIdx.x;  // 64 lanes
    float part[POOLN] = {0.f, 0.f, 0.f, 0.f, 0.f};
    for (int d = l; d < DIN; d += 64) {
        const float cs = colsum[d] * (1.0f / (float)MROWS);
        const float* rp = &lroute[(size_t)1 * DIN * POOLN + (size_t)d * POOLN];
#pragma unroll
        for (int p = 0; p < POOLN; ++p) part[p] += cs * rp[p];
    }
#pragma unroll
    for (int p = 0; p < POOLN; ++p) {
        float v = part[p];
        for (int off = 32; off; off >>= 1) v += __shfl_down(v, off);
        part[p] = v;
    }
    if (l == 0) {
        int tid = *task_id_p;
        if (tid > NTASKS) tid = NTASKS;
        int L = tid < (POOLN - 1) ? tid : (POOLN - 1);   // slice [1:tid+1] clamps
        int k = tid < TOPKK ? tid : TOPKK;
        float sl[POOLN];
        for (int j = 0; j < L; ++j) sl[j] = part[1 + j];
        float G[TOPKK]; int I[TOPKK];
        int used = 0;
        for (int j = 0; j < k; ++j) {
            int best = -1; float bv = 0.f;
            for (int i2 = 0; i2 < L; ++i2) {
                if (used & (1 << i2)) continue;
                if (best < 0 || sl[i2] > bv) { bv = sl[i2]; best = i2; }
            }
            used |= 1 << best; G[j] = bv; I[j] = best;
        }
        if (k > 0) {
            float m = G[0];           // descending -> max first
            float e[TOPKK]; float se = 0.f;
            for (int j = 0; j < k; ++j) { e[j] = expf(G[j] - m); se += e[j]; }
            for (int j = 0; j < k; ++j) { gate[j] = e[j] / se; gidx[j] = I[j]; }
        }
        for (int j = k; j < TOPKK; ++j) { gate[j] = 0.f; gidx[j] = 0; }
    }
}

// ---------------- K3: build two bf16 B^T weight matrices ----------------
__global__ __launch_bounds__(256) void k3_weights(const float* __restrict__ W,
                                                  const float* __restrict__ ldown,
                                                  const float* __restrict__ lup,
                                                  const float* __restrict__ gate,
                                                  const int* __restrict__ gidx,
                                                  __bf16* __restrict__ Wb0,
                                                  __bf16* __restrict__ Wb1) {
    const int o = blockIdx.x;
    const int t = threadIdx.x;
    float c[TOPKK][RR];
#pragma unroll
    for (int j = 0; j < TOPKK; ++j) {
        const float g = gate[j];
        const int   p = gidx[j];
#pragma unroll
        for (int r = 0; r < RR; ++r)
            c[j][r] = g * lup[(size_t)p * RR * DOUT + (size_t)r * DOUT + o];
    }
    const int d0 = t * 4;
    const float4 wv = *(const float4*)&W[(size_t)o * DIN + d0];
    float outv[4] = { wv.x, wv.y, wv.z, wv.w };
    float dwv[4]  = { 0.f, 0.f, 0.f, 0.f };
#pragma unroll
    for (int j = 0; j < TOPKK; ++j) {
        const int p = gidx[j];
#pragma unroll
        for (int dd = 0; dd < 4; ++dd) {
            const float4 da = *(const float4*)&ldown[(size_t)p * DIN * RR + (size_t)(d0 + dd) * RR];
            const float4 db = *(const float4*)&ldown[(size_t)p * DIN * RR + (size_t)(d0 + dd) * RR + 4];
            dwv[dd] += da.x * c[j][0] + da.y * c[j][1] + da.z * c[j][2] + da.w * c[j][3]
                     + db.x * c[j][4] + db.y * c[j][5] + db.z * c[j][6] + db.w * c[j][7];
        }
    }
    bf16x4 b0 = { (__bf16)outv[0], (__bf16)outv[1], (__bf16)outv[2], (__bf16)outv[3] };
    bf16x4 b1 = { (__bf16)(outv[0] + dwv[0]), (__bf16)(outv[1] + dwv[1]),
                  (__bf16)(outv[2] + dwv[2]), (__bf16)(outv[3] + dwv[3]) };
    *(bf16x4*)&Wb0[(size_t)o * DIN + d0] = b0;
    *(bf16x4*)&Wb1[(size_t)o * DIN + d0] = b1;
}

// ---------------- K4: 128x256 bf16 MFMA GEMM, depth-3 slabs, 2 blocks/CU ------
// 512 blocks x 8 waves; wave tile 64x64 (acc 4x4). K = 32 slabs of 32.
// LDS = 3 slabs x (A 8KB + B 16KB) = 72KB -> 2 blocks/CU (144KB, 16 waves/CU).
// Per step: stage(s+2) -> vmcnt(6) [counted, never 0 mid-loop] -> barrier ->
// ds_read+MFMA (setprio 1) -> barrier. Swizzle: [rowpair][slot] 16B units,
// slot = (c+4*parity) ^ (rp&7); inverse applied to per-lane GLOBAL source so
// global_load_lds's linear lane->LDS mapping lands units swizzled (rule #21).
__global__ __launch_bounds__(512, 4) void k4_gemm(const __bf16* __restrict__ A,
                                                  const __bf16* __restrict__ B0,
                                                  const __bf16* __restrict__ B1,
                                                  float* __restrict__ C) {
    __shared__ ushort lds[36864];              // 72 KB; slab p at p*12288 ushorts
    const int bid = blockIdx.x;                // 0..511
    const int xcd = bid & 7;
    const int idx = bid >> 3;                  // 0..63
    const int tm  = xcd * 16 + (idx >> 2);     // 0..127 ; same-XCD blocks share A-panels
    const int tn  = idx & 3;                   // 0..3
    const __bf16* __restrict__ Bt = (tm >= 64) ? B1 : B0;   // rows >= 8192 get +delta

    const int lane = threadIdx.x & 63;
    const int wid  = threadIdx.x >> 6;         // 0..7
    const int wm = wid >> 2, wn = wid & 3;     // 2M x 4N wave grid

    // ---- staging lane geometry (16-row group): unit l holds (row,c):
    const int rpl  = lane >> 3;                // local rowpair 0..7
    const int sl   = (lane & 7) ^ rpl;         // logical c + 4*parity
    const int srow = rpl * 2 + (sl >> 2);      // 0..15
    const int sc   = sl & 3;                   // 16B k-chunk

    // A: wave wid stages rows wid*16..wid*16+15 of the 128-row A slab.
    const char* gA = (const char*)A  + ((size_t)(tm*128 + wid*16 + srow)) * 2048 + sc * 16;
    // B: wave wid stages rows wid*32..wid*32+31 (two 16-row groups) of 256-row B slab.
    const char* gB = (const char*)Bt + ((size_t)(tn*256 + wid*32 + srow)) * 2048 + sc * 16;
    const int ldsAst = wid * 512;              // ushort idx within A region
    const int ldsBst = 4096 + wid * 1024;      // ushort idx within slab (B region)

    // ---- reader lane geometry (validated in R5):
    const int rhalf = (lane & 15) >> 1;
    const int slot  = ((lane >> 4) + 4 * (lane & 1)) ^ rhalf;
    const int aoff  = (wm * 32 + rhalf) * 64 + slot * 8;          // + p*12288 + mi*512
    const int boff  = 4096 + (wn * 32 + rhalf) * 64 + slot * 8;   // + p*12288 + ni*512

    f32x4 acc[4][4];
#pragma unroll
    for (int i = 0; i < 4; ++i)
#pragma unroll
        for (int j = 0; j < 4; ++j) acc[i][j] = (f32x4){0.f, 0.f, 0.f, 0.f};

    auto stageSlab = [&](int s) {
        const int p = s % 3;
        const size_t kb = (size_t)s * 64;      // 32 bf16 = 64 B per k-slab
        __builtin_amdgcn_global_load_lds(
            (const __attribute__((address_space(1))) void*)(gA + kb),
            (__attribute__((address_space(3))) void*)&lds[p * 12288 + ldsAst],
            16, 0, 0);
#pragma unroll
        for (int j = 0; j < 2; ++j) {
            __builtin_amdgcn_global_load_lds(
                (const __attribute__((address_space(1))) void*)(gB + (size_t)j * 32768 + kb),
                (__attribute__((address_space(3))) void*)&lds[p * 12288 + ldsBst + j * 512],
                16, 0, 0);
        }
    };

    auto computeSlab = [&](int s) {
        const int p = s % 3;
        const ushort* aB = &lds[p * 12288 + aoff];
        const ushort* bB = &lds[p * 12288 + boff];
        bf16x8 a[4], b[4];
#pragma unroll
        for (int mi = 0; mi < 4; ++mi) a[mi] = *(const bf16x8*)(aB + mi * 512);
#pragma unroll
        for (int ni = 0; ni < 4; ++ni) b[ni] = *(const bf16x8*)(bB + ni * 512);
        __builtin_amdgcn_s_setprio(1);
#pragma unroll
        for (int mi = 0; mi < 4; ++mi)
#pragma unroll
            for (int ni = 0; ni < 4; ++ni)
                acc[mi][ni] = __builtin_amdgcn_mfma_f32_16x16x32_bf16(
                    a[mi], b[ni], acc[mi][ni], 0, 0, 0);
        __builtin_amdgcn_s_setprio(0);
    };

    // prologue: 2 slabs in flight
    stageSlab(0); stageSlab(1);

#define K4_STEP(S, NSTR, DOSTAGE)                                     \
    {                                                                 \
        if (DOSTAGE) stageSlab((S) + 2);                              \
        asm volatile("s_waitcnt vmcnt(" NSTR ")" ::: "memory");       \
        __builtin_amdgcn_s_barrier();                                 \
        asm volatile("" ::: "memory");                                \
        computeSlab(S);                                               \
        asm volatile("" ::: "memory");                                \
        __builtin_amdgcn_s_barrier();                                 \
    }

#pragma unroll 1
    for (int s = 0; s < 30; ++s) K4_STEP(s, "6", true);
    K4_STEP(30, "3", false);
    K4_STEP(31, "0", false);
#undef K4_STEP

    // epilogue: D col = lane&15, row = (lane>>4)*4 + r
#pragma unroll
    for (int mi = 0; mi < 4; ++mi) {
#pragma unroll
        for (int r = 0; r < 4; ++r) {
            const int grow = tm * 128 + wm * 64 + mi * 16 + (lane >> 4) * 4 + r;
            float* cp = C + (size_t)grow * 1024 + tn * 256 + wn * 64 + (lane & 15);
#pragma unroll
            for (int ni = 0; ni < 4; ++ni) cp[ni * 16] = acc[mi][ni][r];
        }
    }
}

extern "C" void kernel_launch(void* const* d_in, const int* in_sizes, int n_in,
                              void* d_out, int out_size, void* d_ws, size_t ws_size,
                              hipStream_t stream) {
    const float* in     = (const float*)d_in[0];
    const float* W      = (const float*)d_in[1];
    const float* ldown  = (const float*)d_in[2];
    const float* lup    = (const float*)d_in[3];
    const float* lroute = (const float*)d_in[4];
    const int*   taskid = (const int*)d_in[5];
    float* out = (float*)d_out;

    // workspace carve (~36.6 MB)
    __bf16* inB   = (__bf16*)d_ws;                              // 32 MB
    __bf16* Wb0   = inB + (size_t)MROWS * DIN;                  // 2 MB
    __bf16* Wb1   = Wb0 + (size_t)DOUT * DIN;                   // 2 MB
    float*  colsum= (float*)(Wb1 + (size_t)DOUT * DIN);         // 4 KB
    float*  gate  = colsum + DIN;
    int*    gidx  = (int*)(gate + TOPKK);

    // partial colsums live in d_out (8 MB of its 64 MB) — k4 fully overwrites
    // d_out afterwards, so this is deterministic and costs no workspace.
    float* partial = out;

    hipMemsetAsync(colsum, 0, DIN * sizeof(float), stream);
    k1a_stream<<<2048, 256, 0, stream>>>(in, inB, partial);
    k1b_reduce<<<32, 256, 0, stream>>>(partial, colsum);
    k2_gate<<<1, 64, 0, stream>>>(colsum, lroute, taskid, gate, gidx);
    k3_weights<<<1024, 256, 0, stream>>>(W, ldown, lup, gate, gidx, Wb0, Wb1);
    k4_gemm<<<512, 512, 0, stream>>>(inB, Wb0, Wb1, out);
}